// Round 4
// baseline (2443.699 us; speedup 1.0000x reference)
//
#include <hip/hip_runtime.h>
#include <cstdint>

#define B_    64
#define T_    2700
#define HID_  128
#define PRE_  32
#define VMAX_ 256
#define NG_   16   // batch groups = k_scan grid
#define NB_   4    // batches per group
#define TCH_  27   // k_xg t-chunks
#define TSZ_  100  // t per chunk

typedef _Float16 half2_t __attribute__((ext_vector_type(2)));
typedef _Float16 half4_t __attribute__((ext_vector_type(4)));
typedef _Float16 half8_t __attribute__((ext_vector_type(8)));
typedef float    f32x4_t __attribute__((ext_vector_type(4)));
union H8u { half8_t v; half2_t p[4]; };

#define MFMA32(A, Bv, C) __builtin_amdgcn_mfma_f32_16x16x32_f16((A), (Bv), (C), 0, 0, 0)

#if __has_builtin(__builtin_amdgcn_fdot2)
__device__ __forceinline__ float FDOT2(half2_t a, half2_t b, float c) {
    return __builtin_amdgcn_fdot2(a, b, c, false);
}
#else
__device__ __forceinline__ float FDOT2(half2_t a, half2_t b, float c) {
    return c + (float)a[0] * (float)b[0] + (float)a[1] * (float)b[1];
}
#endif

__device__ __forceinline__ half2_t mk2(float a, float b) {
    half2_t r; r[0] = (_Float16)a; r[1] = (_Float16)b; return r;
}
__device__ __forceinline__ float fast_sigmoid(float x) {
    float t = __builtin_amdgcn_exp2f(-1.4426950408889634f * x);
    return __builtin_amdgcn_rcpf(1.0f + t);
}
__device__ __forceinline__ float fast_tanh(float x) {
    float t = __builtin_amdgcn_exp2f(2.885390081777927f * x);
    return 1.0f - 2.0f * __builtin_amdgcn_rcpf(t + 1.0f);
}
template<int CTRL>
__device__ __forceinline__ float dpp_add(float x) {
    int t = __builtin_amdgcn_update_dpp(0, __float_as_int(x), CTRL, 0xF, 0xF, true);
    return x + __int_as_float(t);
}
__device__ __forceinline__ void fma4(float4& a, const float4 w, const float4 h) {
    a.x += w.x * h.x; a.y += w.y * h.y; a.z += w.z * h.z; a.w += w.w * h.w;
}
__device__ __forceinline__ float hsum4(const float4 a) {
    return (a.x + a.y) + (a.z + a.w);
}
// pull the (sel)-th accumulator element from source lane (addr>>2)  [fallback path]
__device__ __forceinline__ float pick_reg(f32x4_t v, int addr, int sel) {
    float t0 = __int_as_float(__builtin_amdgcn_ds_bpermute(addr, __float_as_int(v[0])));
    float t1 = __int_as_float(__builtin_amdgcn_ds_bpermute(addr, __float_as_int(v[1])));
    float t2 = __int_as_float(__builtin_amdgcn_ds_bpermute(addr, __float_as_int(v[2])));
    float t3 = __int_as_float(__builtin_amdgcn_ds_bpermute(addr, __float_as_int(v[3])));
    float a = (sel & 1) ? t1 : t0;
    float b = (sel & 1) ? t3 : t2;
    return (sel & 2) ? b : a;
}

// ---------------------------------------------------------------------------
// Kernel 1: neighborhood assembly + pre = sigmoid(inp @ W_pre.T + b_pre).
// fp16 output packed for K=32 B-fragments: pre16[g][t][hi(4)][cs(4)][j(8)].
// ---------------------------------------------------------------------------
__global__ __launch_bounds__(256) void k_pre(const float* __restrict__ x,
                                             const float* __restrict__ W_pre,
                                             const float* __restrict__ b_pre,
                                             _Float16* __restrict__ pre16) {
    int tid  = blockIdx.x * 256 + threadIdx.x;   // < 64*900*3*32
    int i    = tid & 31;          // k index into PRE
    int rest = tid >> 5;          // (b*900+p)*3 + c
    int c    = rest % 3;
    int r2   = rest / 3;          // b*900 + p
    int p    = r2 % 900;
    int b    = r2 / 900;
    int r    = p / 30;
    int cc   = p - r * 30;
    const float* xb = x + b * 3072 + r * 32 + cc;  // x[b][ch][r][cc] at xb[ch*1024]
    float f0 = xb[0],    f1  = xb[1024], f2  = xb[2048];   // tl
    float f3 = xb[1],    f4  = xb[1025], f5  = xb[2049];   // tc
    float f6 = xb[2],    f7  = xb[1026], f8  = xb[2050];   // tr
    float f9 = xb[32],   f10 = xb[1056], f11 = xb[2080];   // lf
    float ct0 = xb[33],  ct1 = xb[1057];                   // ct[0..1]
    float f12 = (c >= 1) ? ct0 : -1.0f;
    float f13 = (c >= 2) ? ct1 : -1.0f;
    const float* w = W_pre + i * 14;
    float d = b_pre[i];
    d += f0*w[0]  + f1*w[1]  + f2*w[2]  + f3*w[3]  + f4*w[4]  + f5*w[5]  + f6*w[6]
       + f7*w[7]  + f8*w[8]  + f9*w[9]  + f10*w[10] + f11*w[11] + f12*w[12] + f13*w[13];

    int t  = p * 3 + c;           // time index
    int g  = b >> 2;              // batch group
    int cs = b & 3;               // batch slot within group
    size_t base = ((size_t)g * T_ + t) * 128;     // 128 halves per (g,t)
    int idx = ((i >> 3) << 5) | (cs << 3) | (i & 7);   // [hi][cs][j]
    pre16[base + idx] = (_Float16)fast_sigmoid(d);
}

// ---------------------------------------------------------------------------
// Kernel 1b (FULL): xg[g][t][(w,hi,c,reg)] = {xr',xz',xn',0} fp16, where
// tid = w(3b)|hi(2b)|c(2b)|reg(2b), u = w*16+hi*4+reg. k_scan's active lane
// (w,hi,c) reads its 4 rows' gate pre-activations with two b128 loads.
// xr' = pre.Wr + b_ih_r + b_hh_r; xz' likewise; xn' = pre.Wn + b_ih_n.
// ---------------------------------------------------------------------------
__global__ __launch_bounds__(512) void k_xg_full(const float* __restrict__ W_ih,
                                                 const float* __restrict__ b_ih,
                                                 const float* __restrict__ b_hh,
                                                 const _Float16* __restrict__ pre16,
                                                 _Float16* __restrict__ xg16) {
    const int tid = threadIdx.x;
    const int g   = blockIdx.x / TCH_;
    const int tc  = blockIdx.x % TCH_;
    const int u3  = ((tid >> 6) << 4) | (((tid >> 4) & 3) << 2) | (tid & 3);
    const int c4  = (tid >> 2) & 3;

    half2_t wr[16], wz[16], wn[16];
    const float* Wr = W_ih + (size_t)u3 * PRE_;
    const float* Wz = W_ih + (size_t)(128 + u3) * PRE_;
    const float* Wn = W_ih + (size_t)(256 + u3) * PRE_;
#pragma unroll
    for (int k2 = 0; k2 < 16; ++k2) {
        wr[k2] = mk2(Wr[2*k2], Wr[2*k2 + 1]);
        wz[k2] = mk2(Wz[2*k2], Wz[2*k2 + 1]);
        wn[k2] = mk2(Wn[2*k2], Wn[2*k2 + 1]);
    }
    const float br = b_ih[u3] + b_hh[u3];
    const float bz = b_ih[128 + u3] + b_hh[128 + u3];
    const float bn = b_ih[256 + u3];

    const char* preg = (const char*)pre16 + ((size_t)g * T_ + (size_t)tc * TSZ_) * 256 + c4 * 16;
    H8u pc0, pc1, pc2, pc3;
    pc0.v = *(const half8_t*)(preg +   0);
    pc1.v = *(const half8_t*)(preg +  64);
    pc2.v = *(const half8_t*)(preg + 128);
    pc3.v = *(const half8_t*)(preg + 192);

    for (int tt = 0; tt < TSZ_; ++tt) {
        const int ttn = (tt + 1 < TSZ_) ? tt + 1 : tt;
        H8u n0, n1, n2, n3;
        n0.v = *(const half8_t*)(preg + (size_t)ttn * 256 +   0);
        n1.v = *(const half8_t*)(preg + (size_t)ttn * 256 +  64);
        n2.v = *(const half8_t*)(preg + (size_t)ttn * 256 + 128);
        n3.v = *(const half8_t*)(preg + (size_t)ttn * 256 + 192);

        float ar = br, az = bz, an = bn;
#pragma unroll
        for (int j2 = 0; j2 < 4; ++j2) { ar = FDOT2(wr[ 0+j2], pc0.p[j2], ar); az = FDOT2(wz[ 0+j2], pc0.p[j2], az); an = FDOT2(wn[ 0+j2], pc0.p[j2], an); }
#pragma unroll
        for (int j2 = 0; j2 < 4; ++j2) { ar = FDOT2(wr[ 4+j2], pc1.p[j2], ar); az = FDOT2(wz[ 4+j2], pc1.p[j2], az); an = FDOT2(wn[ 4+j2], pc1.p[j2], an); }
#pragma unroll
        for (int j2 = 0; j2 < 4; ++j2) { ar = FDOT2(wr[ 8+j2], pc2.p[j2], ar); az = FDOT2(wz[ 8+j2], pc2.p[j2], az); an = FDOT2(wn[ 8+j2], pc2.p[j2], an); }
#pragma unroll
        for (int j2 = 0; j2 < 4; ++j2) { ar = FDOT2(wr[12+j2], pc3.p[j2], ar); az = FDOT2(wz[12+j2], pc3.p[j2], az); an = FDOT2(wn[12+j2], pc3.p[j2], an); }

        const size_t t = (size_t)tc * TSZ_ + tt;
        half4_t o;
        o[0] = (_Float16)ar; o[1] = (_Float16)az; o[2] = (_Float16)an; o[3] = (_Float16)0.f;
        *(half4_t*)((char*)xg16 + (((size_t)g * T_ + t) * 512 + tid) * 8) = o;
        pc0 = n0; pc1 = n1; pc2 = n2; pc3 = n3;
    }
}

// ---------------------------------------------------------------------------
// Kernel 1b (fallback): only the xn' plane, old tid mapping (u3,c4).
// ---------------------------------------------------------------------------
__global__ __launch_bounds__(512) void k_xg_fb(const float* __restrict__ W_ih,
                                               const float* __restrict__ b_ih,
                                               const _Float16* __restrict__ pre16,
                                               _Float16* __restrict__ xg16) {
    const int tid = threadIdx.x;
    const int g   = blockIdx.x / TCH_;
    const int tc  = blockIdx.x % TCH_;
    const int u3  = (tid >> 6) * 16 + ((tid & 63) >> 2);
    const int c4  = tid & 3;

    half2_t wn[16];
    const float* Wn = W_ih + (size_t)(256 + u3) * PRE_;
#pragma unroll
    for (int k2 = 0; k2 < 16; ++k2) wn[k2] = mk2(Wn[2*k2], Wn[2*k2 + 1]);
    const float bn = b_ih[256 + u3];

    const char* preg = (const char*)pre16 + ((size_t)g * T_ + (size_t)tc * TSZ_) * 256 + c4 * 16;
    for (int tt = 0; tt < TSZ_; ++tt) {
        H8u pc0, pc1, pc2, pc3;
        pc0.v = *(const half8_t*)(preg + (size_t)tt * 256 +   0);
        pc1.v = *(const half8_t*)(preg + (size_t)tt * 256 +  64);
        pc2.v = *(const half8_t*)(preg + (size_t)tt * 256 + 128);
        pc3.v = *(const half8_t*)(preg + (size_t)tt * 256 + 192);
        float an = bn;
#pragma unroll
        for (int j2 = 0; j2 < 4; ++j2) an = FDOT2(wn[ 0+j2], pc0.p[j2], an);
#pragma unroll
        for (int j2 = 0; j2 < 4; ++j2) an = FDOT2(wn[ 4+j2], pc1.p[j2], an);
#pragma unroll
        for (int j2 = 0; j2 < 4; ++j2) an = FDOT2(wn[ 8+j2], pc2.p[j2], an);
#pragma unroll
        for (int j2 = 0; j2 < 4; ++j2) an = FDOT2(wn[12+j2], pc3.p[j2], an);
        const size_t t = (size_t)tc * TSZ_ + tt;
        xg16[((size_t)g * T_ + t) * 512 + tid] = (_Float16)an;
    }
}

// ---------------------------------------------------------------------------
// Kernel 2 (FULL): persistent GRU scan v4 — direct epilogue, no bpermute.
// 16 blocks x 512 thr, 4 batch chains each. Wave w: 12 MFMA 16x16x32 (r,z,n
// over K=128). D layout (col=lane&15, row=4*(lane>>4)+reg): lanes with
// (lane&15)<4 hold r/z/n for 4 gate-rows of their batch col IN REGISTERS ->
// they run the 4 nonlinearities directly (trans pipe), write h via one
// conflict-free ds_write_b64, store hs via one 8B global store. t-loop
// unrolled x2 (static hbuf indices); xg prefetched 2 steps ahead. Raw
// lgkmcnt(0)+s_barrier keeps vmem in flight across the barrier.
// ---------------------------------------------------------------------------
__global__ __launch_bounds__(512, 1) void k_scan_full(const float* __restrict__ W_hh,
                                                      const float* __restrict__ b_hh,
                                                      const _Float16* __restrict__ xg16,
                                                      _Float16* __restrict__ hs16) {
    __shared__ __align__(16) _Float16 hbuf[2][4][4][4][8];   // 2 KB

    const int tid  = threadIdx.x;
    const int g    = blockIdx.x;
    const int w    = tid >> 6;
    const int lane = tid & 63;
    const int lo   = lane & 15;
    const int hi   = lane >> 4;
    const int c4   = lane & 3;
    const int row  = w * 16 + lo;

    half8_t Ar[4], Az[4], Ahn[4];
#pragma unroll
    for (int kc = 0; kc < 4; ++kc) {
        half8_t ar, az, an;
#pragma unroll
        for (int j = 0; j < 8; ++j) {
            int k = kc * 32 + hi * 8 + j;
            ar[j] = (_Float16)W_hh[row * HID_ + k];
            az[j] = (_Float16)W_hh[(128 + row) * HID_ + k];
            an[j] = (_Float16)W_hh[(256 + row) * HID_ + k];
        }
        Ar[kc] = ar; Az[kc] = az; Ahn[kc] = an;
    }

    const bool act = (lo < 4);
    const int u0 = w * 16 + hi * 4;     // active lane's first gate-row
    const f32x4_t bhn4 = *(const f32x4_t*)(b_hh + 256 + u0);

    const char* xgp = (const char*)xg16 + (size_t)g * T_ * 4096
                    + (size_t)(((w << 4) | (hi << 2) | c4) << 5);
    _Float16* hsb = hs16 + (size_t)(g * NB_ + c4) * T_ * HID_ + u0;

    const int kc_w  = u0 >> 5;
    const int hi2_w = (u0 >> 3) & 3;
    const int j0_w  = u0 & 7;

    ((uint32_t*)hbuf)[tid] = 0u;        // zero-init both buffers

    half8_t xA0 = *(const half8_t*)(xgp);
    half8_t xA1 = *(const half8_t*)(xgp + 16);
    half8_t xB0 = *(const half8_t*)(xgp + 4096);
    half8_t xB1 = *(const half8_t*)(xgp + 4096 + 16);
    f32x4_t hp = {0.f, 0.f, 0.f, 0.f};
    __syncthreads();

#define SCAN_STEP(RB, X0, X1, TT)                                              \
    {                                                                          \
        half8_t hB0 = *(const half8_t*)&hbuf[RB][0][hi][c4][0];                \
        half8_t hB1 = *(const half8_t*)&hbuf[RB][1][hi][c4][0];                \
        half8_t hB2 = *(const half8_t*)&hbuf[RB][2][hi][c4][0];                \
        half8_t hB3 = *(const half8_t*)&hbuf[RB][3][hi][c4][0];                \
        f32x4_t r = {0.f,0.f,0.f,0.f}, z = {0.f,0.f,0.f,0.f}, n = {0.f,0.f,0.f,0.f}; \
        r = MFMA32(Ar[0], hB0, r); z = MFMA32(Az[0], hB0, z); n = MFMA32(Ahn[0], hB0, n); \
        r = MFMA32(Ar[1], hB1, r); z = MFMA32(Az[1], hB1, z); n = MFMA32(Ahn[1], hB1, n); \
        r = MFMA32(Ar[2], hB2, r); z = MFMA32(Az[2], hB2, z); n = MFMA32(Ahn[2], hB2, n); \
        r = MFMA32(Ar[3], hB3, r); z = MFMA32(Az[3], hB3, z); n = MFMA32(Ahn[3], hB3, n); \
        if (act) {                                                             \
            half4_t hq;                                                        \
            _Pragma("unroll")                                                  \
            for (int q = 0; q < 4; ++q) {                                      \
                half8_t xv = (q < 2) ? (X0) : (X1);                            \
                const int o = (q & 1) * 4;                                     \
                float rg = fast_sigmoid(r[q] + (float)xv[o]);                  \
                float zg = fast_sigmoid(z[q] + (float)xv[o + 1]);              \
                float ng = fast_tanh((float)xv[o + 2] + rg * (n[q] + bhn4[q])); \
                float hv = ng + zg * (hp[q] - ng);                             \
                hp[q] = hv;                                                    \
                hq[q] = (_Float16)hv;                                          \
            }                                                                  \
            *(half4_t*)&hbuf[(RB) ^ 1][kc_w][hi2_w][c4][j0_w] = hq;            \
            *(half4_t*)(hsb + (size_t)(TT) * HID_) = hq;                       \
        }                                                                      \
        asm volatile("s_waitcnt lgkmcnt(0)" ::: "memory");                     \
        __builtin_amdgcn_s_barrier();                                          \
    }

    for (int t = 0; t < T_; t += 2) {
        const size_t o2 = (size_t)((t + 2 < T_) ? t + 2 : T_ - 1) * 4096;
        const size_t o3 = (size_t)((t + 3 < T_) ? t + 3 : T_ - 1) * 4096;
        half8_t xC0 = *(const half8_t*)(xgp + o2);
        half8_t xC1 = *(const half8_t*)(xgp + o2 + 16);
        SCAN_STEP(0, xA0, xA1, t);
        half8_t xD0 = *(const half8_t*)(xgp + o3);
        half8_t xD1 = *(const half8_t*)(xgp + o3 + 16);
        SCAN_STEP(1, xB0, xB1, t + 1);
        xA0 = xC0; xA1 = xC1; xB0 = xD0; xB1 = xD1;
    }
#undef SCAN_STEP
}

// ---------------------------------------------------------------------------
// Kernel 2 (fallback, ws too small for full xg): round-3 bpermute version.
// ---------------------------------------------------------------------------
__global__ __launch_bounds__(512, 1) void k_scan_fb(const float* __restrict__ W_ih,
                                                    const float* __restrict__ b_ih,
                                                    const float* __restrict__ W_hh,
                                                    const float* __restrict__ b_hh,
                                                    const _Float16* __restrict__ pre16,
                                                    const _Float16* __restrict__ xg16,
                                                    _Float16* __restrict__ hs16) {
    __shared__ __align__(16) _Float16 hbuf[2][4][4][4][8];
    const int tid  = threadIdx.x;
    const int g    = blockIdx.x;
    const int w    = tid >> 6;
    const int lane = tid & 63;
    const int lo   = lane & 15;
    const int hi   = lane >> 4;
    const int c4   = lane & 3;
    const int row  = w * 16 + lo;

    half8_t Ar[5], Az[5], Ahn[4];
#pragma unroll
    for (int kc = 0; kc < 4; ++kc) {
        half8_t ar, az, an;
#pragma unroll
        for (int j = 0; j < 8; ++j) {
            int k = kc * 32 + hi * 8 + j;
            ar[j] = (_Float16)W_hh[row * HID_ + k];
            az[j] = (_Float16)W_hh[(128 + row) * HID_ + k];
            an[j] = (_Float16)W_hh[(256 + row) * HID_ + k];
        }
        Ar[kc] = ar; Az[kc] = az; Ahn[kc] = an;
    }
    {
        half8_t ar, az;
#pragma unroll
        for (int j = 0; j < 8; ++j) {
            int k = hi * 8 + j;
            ar[j] = (_Float16)W_ih[row * PRE_ + k];
            az[j] = (_Float16)W_ih[(128 + row) * PRE_ + k];
        }
        Ar[4] = ar; Az[4] = az;
    }

    const int u3 = w * 16 + (lane >> 2);
    const float br  = b_ih[u3] + b_hh[u3];
    const float bz  = b_ih[128 + u3] + b_hh[128 + u3];
    const float bhn = b_hh[256 + u3];
    const int srcaddr = ((((lane >> 4) << 4) | c4) << 2);
    const int sel     = (lane >> 2) & 3;

    const char* preg  = (const char*)pre16 + (size_t)g * T_ * 256;
    const int   pfoff = hi * 64 + c4 * 16;
    const _Float16* xgs = xg16 + (size_t)g * T_ * 512 + tid;
    _Float16* hsb = hs16 + (size_t)(g * NB_ + c4) * T_ * HID_ + u3;

    const int kc_w = u3 >> 5;
    const int hi_w = (u3 >> 3) & 3;
    const int j_w  = u3 & 7;

    ((uint32_t*)hbuf)[tid] = 0u;

    half8_t pf = *(const half8_t*)(preg + pfoff);
    _Float16 xnf = xgs[0];
    float hprev = 0.0f;
    __syncthreads();

    for (int t = 0; t < T_; ++t) {
        const int tn = (t + 1 < T_) ? (t + 1) : t;
        half8_t pfn = *(const half8_t*)(preg + (size_t)tn * 256 + pfoff);
        _Float16 xnn = xgs[(size_t)tn * 512];

        const int rb = t & 1;
        half8_t hB[4];
#pragma unroll
        for (int kc = 0; kc < 4; ++kc)
            hB[kc] = *(const half8_t*)&hbuf[rb][kc][hi][c4][0];

        const f32x4_t Z4 = {0.f, 0.f, 0.f, 0.f};
        f32x4_t r = Z4, z = Z4, n = Z4;
        r = MFMA32(Ar[0],  hB[0], r);
        z = MFMA32(Az[0],  hB[0], z);
        n = MFMA32(Ahn[0], hB[0], n);
        r = MFMA32(Ar[1],  hB[1], r);
        z = MFMA32(Az[1],  hB[1], z);
        n = MFMA32(Ahn[1], hB[1], n);
        r = MFMA32(Ar[2],  hB[2], r);
        z = MFMA32(Az[2],  hB[2], z);
        n = MFMA32(Ahn[2], hB[2], n);
        r = MFMA32(Ar[3],  hB[3], r);
        z = MFMA32(Az[3],  hB[3], z);
        n = MFMA32(Ahn[3], hB[3], n);
        r = MFMA32(Ar[4], pf, r);
        z = MFMA32(Az[4], pf, z);

        float srr = pick_reg(r, srcaddr, sel) + br;
        float szz = pick_reg(z, srcaddr, sel) + bz;
        float shn = pick_reg(n, srcaddr, sel) + bhn;
        float sxn = (float)xnf;

        float rg   = fast_sigmoid(srr);
        float zg   = fast_sigmoid(szz);
        float ng   = fast_tanh(sxn + rg * shn);
        float hnew = ng + zg * (hprev - ng);
        hprev = hnew;
        _Float16 h16 = (_Float16)hnew;

        hbuf[rb ^ 1][kc_w][hi_w][c4][j_w] = h16;
        hsb[(size_t)t * HID_] = h16;

        pf = pfn; xnf = xnn;
        asm volatile("s_waitcnt lgkmcnt(0)" ::: "memory");
        __builtin_amdgcn_s_barrier();
    }
}

// ---------------------------------------------------------------------------
// Kernel 3: out = hs @ W_post.T + b_post into padded NCHWV layout (fp16 hs).
// ---------------------------------------------------------------------------
__global__ __launch_bounds__(512, 4) void k_post(const float* __restrict__ W_post,
                                                 const float* __restrict__ b_post,
                                                 const _Float16* __restrict__ hs,
                                                 float* __restrict__ out) {
    __shared__ __align__(16) float sh[2][HID_];
    const int tid  = threadIdx.x;
    const int v    = tid >> 1;
    const int hf   = tid & 1;
    const int blk  = blockIdx.x;       // 64*3*32
    const int i    = blk & 31;
    const int rest = blk >> 5;
    const int ch   = rest % 3;
    const int b    = rest / 3;
    float* outb = out + ((size_t)(b * 3 + ch) * 1024 + i * 32) * VMAX_;

    if (i == 0 || i == 31) {
        if (hf == 0) {
#pragma unroll
            for (int jc = 0; jc < 32; ++jc) outb[jc * VMAX_ + v] = 0.0f;
        }
        return;
    }

    float4 wp[16];
    const float4* wpp = (const float4*)(W_post + (size_t)v * HID_ + hf * 64);
#pragma unroll
    for (int k = 0; k < 16; ++k) wp[k] = wpp[k];
    const float bp = b_post[v];

    const _Float16* hsb = hs + (size_t)b * T_ * HID_;
    const int trow = (i - 1) * 30;     // t = (trow + (jc-1))*3 + ch

    if (tid < 32) {
        half4_t hv = ((const half4_t*)(hsb + (size_t)(trow * 3 + ch) * HID_))[tid];
        float4 f = {(float)hv[0], (float)hv[1], (float)hv[2], (float)hv[3]};
        ((float4*)sh[1])[tid] = f;
    }
    if (hf == 0) { outb[v] = 0.0f; outb[31 * VMAX_ + v] = 0.0f; }
    __syncthreads();

    for (int jc = 1; jc <= 30; ++jc) {
        if (tid < 32 && jc < 30) {
            half4_t hv = ((const half4_t*)(hsb + (size_t)((trow + jc) * 3 + ch) * HID_))[tid];
            float4 f = {(float)hv[0], (float)hv[1], (float)hv[2], (float)hv[3]};
            ((float4*)sh[(jc + 1) & 1])[tid] = f;
        }
        const float4* h4 = (const float4*)sh[jc & 1] + hf * 16;
        float4 a0 = {0,0,0,0}, a1 = {0,0,0,0}, a2 = {0,0,0,0}, a3 = {0,0,0,0};
#pragma unroll
        for (int k = 0; k < 16; k += 4) {
            fma4(a0, wp[k],     h4[k]);
            fma4(a1, wp[k + 1], h4[k + 1]);
            fma4(a2, wp[k + 2], h4[k + 2]);
            fma4(a3, wp[k + 3], h4[k + 3]);
        }
        float s = (hsum4(a0) + hsum4(a1)) + (hsum4(a2) + hsum4(a3));
        s = dpp_add<0xB1>(s);
        if (hf == 0) outb[jc * VMAX_ + v] = bp + s;
        __syncthreads();
    }
}

extern "C" void kernel_launch(void* const* d_in, const int* in_sizes, int n_in,
                              void* d_out, int out_size, void* d_ws, size_t ws_size,
                              hipStream_t stream) {
    const float* x      = (const float*)d_in[0];
    const float* W_pre  = (const float*)d_in[1];
    const float* b_pre  = (const float*)d_in[2];
    const float* W_ih   = (const float*)d_in[3];
    const float* b_ih   = (const float*)d_in[4];
    const float* W_hh   = (const float*)d_in[5];
    const float* b_hh   = (const float*)d_in[6];
    const float* W_post = (const float*)d_in[7];
    const float* b_post = (const float*)d_in[8];
    float* out = (float*)d_out;

    const size_t pre_bytes = (size_t)NG_ * T_ * 256;       // 11.06 MB
    const size_t xg_full   = (size_t)NG_ * T_ * 512 * 8;   // 176.9 MB
    const size_t xg_fb     = (size_t)NG_ * T_ * 512 * 2;   // 44.2 MB
    const size_t hs_bytes  = (size_t)B_ * T_ * HID_ * 2;   // 44.2 MB
    const bool full = ws_size >= pre_bytes + xg_full + hs_bytes;

    _Float16* pre16 = (_Float16*)d_ws;
    _Float16* xg    = (_Float16*)((char*)d_ws + pre_bytes);
    _Float16* hs16  = (_Float16*)((char*)d_ws + pre_bytes + (full ? xg_full : xg_fb));

    k_pre<<<21600, 256, 0, stream>>>(x, W_pre, b_pre, pre16);
    if (full) {
        k_xg_full<<<NG_ * TCH_, 512, 0, stream>>>(W_ih, b_ih, b_hh, pre16, xg);
        k_scan_full<<<NG_, 512, 0, stream>>>(W_hh, b_hh, xg, hs16);
    } else {
        k_xg_fb<<<NG_ * TCH_, 512, 0, stream>>>(W_ih, b_ih, pre16, xg);
        k_scan_fb<<<NG_, 512, 0, stream>>>(W_ih, b_ih, W_hh, b_hh, pre16, xg, hs16);
    }
    k_post<<<6144, 512, 0, stream>>>(W_post, b_post, hs16, out);
}

// Round 5
// 2117.524 us; speedup vs baseline: 1.1540x; 1.1540x over previous
//
#include <hip/hip_runtime.h>
#include <cstdint>

#define B_    64
#define T_    2700
#define HID_  128
#define PRE_  32
#define VMAX_ 256
#define NG_   16   // batch groups = k_scan grid
#define NB_   4    // batches per group
#define TCH_  27   // k_xg t-chunks
#define TSZ_  100  // t per chunk

typedef _Float16 half2_t __attribute__((ext_vector_type(2)));
typedef _Float16 half4_t __attribute__((ext_vector_type(4)));
typedef _Float16 half8_t __attribute__((ext_vector_type(8)));
typedef float    f32x4_t __attribute__((ext_vector_type(4)));
union H8u { half8_t v; half2_t p[4]; };

#define MFMA32(A, Bv, C) __builtin_amdgcn_mfma_f32_16x16x32_f16((A), (Bv), (C), 0, 0, 0)

#if __has_builtin(__builtin_amdgcn_fdot2)
__device__ __forceinline__ float FDOT2(half2_t a, half2_t b, float c) {
    return __builtin_amdgcn_fdot2(a, b, c, false);
}
#else
__device__ __forceinline__ float FDOT2(half2_t a, half2_t b, float c) {
    return c + (float)a[0] * (float)b[0] + (float)a[1] * (float)b[1];
}
#endif

__device__ __forceinline__ half2_t mk2(float a, float b) {
    half2_t r; r[0] = (_Float16)a; r[1] = (_Float16)b; return r;
}
__device__ __forceinline__ float fast_sigmoid(float x) {
    float t = __builtin_amdgcn_exp2f(-1.4426950408889634f * x);
    return __builtin_amdgcn_rcpf(1.0f + t);
}
__device__ __forceinline__ float fast_tanh(float x) {
    float t = __builtin_amdgcn_exp2f(2.885390081777927f * x);
    return 1.0f - 2.0f * __builtin_amdgcn_rcpf(t + 1.0f);
}
// pull the (sel)-th accumulator element from source lane (addr>>2)
__device__ __forceinline__ float pick_reg(f32x4_t v, int addr, int sel) {
    float t0 = __int_as_float(__builtin_amdgcn_ds_bpermute(addr, __float_as_int(v[0])));
    float t1 = __int_as_float(__builtin_amdgcn_ds_bpermute(addr, __float_as_int(v[1])));
    float t2 = __int_as_float(__builtin_amdgcn_ds_bpermute(addr, __float_as_int(v[2])));
    float t3 = __int_as_float(__builtin_amdgcn_ds_bpermute(addr, __float_as_int(v[3])));
    float a = (sel & 1) ? t1 : t0;
    float b = (sel & 1) ? t3 : t2;
    return (sel & 2) ? b : a;
}

// ---------------------------------------------------------------------------
// Kernel 1: neighborhood assembly + pre = sigmoid(inp @ W_pre.T + b_pre).
// fp16 output packed for K=32 B-fragments: pre16[g][t][hi(4)][cs(4)][j(8)].
// ---------------------------------------------------------------------------
__global__ __launch_bounds__(256) void k_pre(const float* __restrict__ x,
                                             const float* __restrict__ W_pre,
                                             const float* __restrict__ b_pre,
                                             _Float16* __restrict__ pre16) {
    int tid  = blockIdx.x * 256 + threadIdx.x;   // < 64*900*3*32
    int i    = tid & 31;          // k index into PRE
    int rest = tid >> 5;          // (b*900+p)*3 + c
    int c    = rest % 3;
    int r2   = rest / 3;          // b*900 + p
    int p    = r2 % 900;
    int b    = r2 / 900;
    int r    = p / 30;
    int cc   = p - r * 30;
    const float* xb = x + b * 3072 + r * 32 + cc;  // x[b][ch][r][cc] at xb[ch*1024]
    float f0 = xb[0],    f1  = xb[1024], f2  = xb[2048];   // tl
    float f3 = xb[1],    f4  = xb[1025], f5  = xb[2049];   // tc
    float f6 = xb[2],    f7  = xb[1026], f8  = xb[2050];   // tr
    float f9 = xb[32],   f10 = xb[1056], f11 = xb[2080];   // lf
    float ct0 = xb[33],  ct1 = xb[1057];                   // ct[0..1]
    float f12 = (c >= 1) ? ct0 : -1.0f;
    float f13 = (c >= 2) ? ct1 : -1.0f;
    const float* w = W_pre + i * 14;
    float d = b_pre[i];
    d += f0*w[0]  + f1*w[1]  + f2*w[2]  + f3*w[3]  + f4*w[4]  + f5*w[5]  + f6*w[6]
       + f7*w[7]  + f8*w[8]  + f9*w[9]  + f10*w[10] + f11*w[11] + f12*w[12] + f13*w[13];

    int t  = p * 3 + c;           // time index
    int g  = b >> 2;              // batch group
    int cs = b & 3;               // batch slot within group
    size_t base = ((size_t)g * T_ + t) * 128;     // 128 halves per (g,t)
    int idx = ((i >> 3) << 5) | (cs << 3) | (i & 7);   // [hi][cs][j]
    pre16[base + idx] = (_Float16)fast_sigmoid(d);
}

// ---------------------------------------------------------------------------
// Kernel 1b: xg[g][t][tid] = {xr', xz', xn', 0} fp16 (8B/thread), where
// u3 = (tid>>6)*16 + ((tid&63)>>2), c4 = tid&3 — matches k_scan's lane
// ownership exactly, so k_scan loads its values with one coalesced 8B load.
// xr' = pre.Wr + b_ih_r + b_hh_r; xz' likewise; xn' = pre.Wn + b_ih_n.
// (round-3 proven layout)
// ---------------------------------------------------------------------------
__global__ __launch_bounds__(512) void k_xg(const float* __restrict__ W_ih,
                                            const float* __restrict__ b_ih,
                                            const float* __restrict__ b_hh,
                                            const _Float16* __restrict__ pre16,
                                            _Float16* __restrict__ xg16) {
    const int tid = threadIdx.x;
    const int g   = blockIdx.x / TCH_;
    const int tc  = blockIdx.x % TCH_;
    const int u3  = (tid >> 6) * 16 + ((tid & 63) >> 2);
    const int c4  = tid & 3;

    half2_t wr[16], wz[16], wn[16];
    const float* Wr = W_ih + (size_t)u3 * PRE_;
    const float* Wz = W_ih + (size_t)(128 + u3) * PRE_;
    const float* Wn = W_ih + (size_t)(256 + u3) * PRE_;
#pragma unroll
    for (int k2 = 0; k2 < 16; ++k2) {
        wr[k2] = mk2(Wr[2*k2], Wr[2*k2 + 1]);
        wz[k2] = mk2(Wz[2*k2], Wz[2*k2 + 1]);
        wn[k2] = mk2(Wn[2*k2], Wn[2*k2 + 1]);
    }
    const float br = b_ih[u3] + b_hh[u3];
    const float bz = b_ih[128 + u3] + b_hh[128 + u3];
    const float bn = b_ih[256 + u3];

    const char* preg = (const char*)pre16 + ((size_t)g * T_ + (size_t)tc * TSZ_) * 256 + c4 * 16;
    H8u pc0, pc1, pc2, pc3;
    pc0.v = *(const half8_t*)(preg +   0);
    pc1.v = *(const half8_t*)(preg +  64);
    pc2.v = *(const half8_t*)(preg + 128);
    pc3.v = *(const half8_t*)(preg + 192);

    for (int tt = 0; tt < TSZ_; ++tt) {
        const int ttn = (tt + 1 < TSZ_) ? tt + 1 : tt;
        H8u n0, n1, n2, n3;
        n0.v = *(const half8_t*)(preg + (size_t)ttn * 256 +   0);
        n1.v = *(const half8_t*)(preg + (size_t)ttn * 256 +  64);
        n2.v = *(const half8_t*)(preg + (size_t)ttn * 256 + 128);
        n3.v = *(const half8_t*)(preg + (size_t)ttn * 256 + 192);

        float ar = br, az = bz, an = bn;
#pragma unroll
        for (int j2 = 0; j2 < 4; ++j2) { ar = FDOT2(wr[ 0+j2], pc0.p[j2], ar); az = FDOT2(wz[ 0+j2], pc0.p[j2], az); an = FDOT2(wn[ 0+j2], pc0.p[j2], an); }
#pragma unroll
        for (int j2 = 0; j2 < 4; ++j2) { ar = FDOT2(wr[ 4+j2], pc1.p[j2], ar); az = FDOT2(wz[ 4+j2], pc1.p[j2], az); an = FDOT2(wn[ 4+j2], pc1.p[j2], an); }
#pragma unroll
        for (int j2 = 0; j2 < 4; ++j2) { ar = FDOT2(wr[ 8+j2], pc2.p[j2], ar); az = FDOT2(wz[ 8+j2], pc2.p[j2], az); an = FDOT2(wn[ 8+j2], pc2.p[j2], an); }
#pragma unroll
        for (int j2 = 0; j2 < 4; ++j2) { ar = FDOT2(wr[12+j2], pc3.p[j2], ar); az = FDOT2(wz[12+j2], pc3.p[j2], az); an = FDOT2(wn[12+j2], pc3.p[j2], an); }

        const size_t t = (size_t)tc * TSZ_ + tt;
        half4_t o;
        o[0] = (_Float16)ar; o[1] = (_Float16)az; o[2] = (_Float16)an; o[3] = (_Float16)0.f;
        *(half4_t*)((char*)xg16 + (((size_t)g * T_ + t) * 512 + tid) * 8) = o;
        pc0 = n0; pc1 = n1; pc2 = n2; pc3 = n3;
    }
}

// ---------------------------------------------------------------------------
// Kernel 1c: W_post -> fp16, row-major [256][128] (B-fragment loads become
// one b128 per kc). Written into the dead pre16 region (runs after k_xg).
// ---------------------------------------------------------------------------
__global__ __launch_bounds__(256) void k_wcvt(const float* __restrict__ W_post,
                                              _Float16* __restrict__ w16) {
    int idx = blockIdx.x * 256 + threadIdx.x;   // 32768
    w16[idx] = (_Float16)W_post[idx];
}

// ---------------------------------------------------------------------------
// Kernel 2: persistent GRU scan v5 = round-3 structure (proven 1408 us) +
// x2 unroll (static double-buffer indices) + 2-step xg prefetch.
// 16 blocks x 512 thr, 4 batch chains each; wave w owns gate rows
// [16w,16w+16); 12 MFMA 16x16x32 per wave; bpermute epilogue (1 nonlinearity
// per lane — round-4 showed concentrating it into 16 lanes quadruples issue
// cost); raw lgkmcnt(0)+s_barrier keeps vmem in flight across the barrier.
// ---------------------------------------------------------------------------
__global__ __launch_bounds__(512, 1) void k_scan(const float* __restrict__ W_hh,
                                                 const float* __restrict__ b_hh,
                                                 const _Float16* __restrict__ xg16,
                                                 _Float16* __restrict__ hs16) {
    // h state in B-frag layout: [buf][kc][hi][c][j], u = kc*32 + hi*8 + j
    __shared__ __align__(16) _Float16 hbuf[2][4][4][4][8];   // 2 KB

    const int tid  = threadIdx.x;
    const int g    = blockIdx.x;
    const int w    = tid >> 6;
    const int lane = tid & 63;
    const int lo   = lane & 15;
    const int hi   = lane >> 4;
    const int c4   = lane & 3;
    const int row  = w * 16 + lo;

    half8_t Ar[4], Az[4], Ahn[4];
#pragma unroll
    for (int kc = 0; kc < 4; ++kc) {
        half8_t ar, az, an;
#pragma unroll
        for (int j = 0; j < 8; ++j) {
            int k = kc * 32 + hi * 8 + j;
            ar[j] = (_Float16)W_hh[row * HID_ + k];
            az[j] = (_Float16)W_hh[(128 + row) * HID_ + k];
            an[j] = (_Float16)W_hh[(256 + row) * HID_ + k];
        }
        Ar[kc] = ar; Az[kc] = az; Ahn[kc] = an;
    }

    const int u3 = w * 16 + (lane >> 2);
    const float bhn = b_hh[256 + u3];
    const int srcaddr = ((((lane >> 4) << 4) | c4) << 2);
    const int sel     = (lane >> 2) & 3;

    const char* xgp = (const char*)xg16 + ((size_t)g * T_ * 512 + tid) * 8;
    _Float16* hsb = hs16 + (size_t)(g * NB_ + c4) * T_ * HID_ + u3;

    const int kc_w = u3 >> 5;
    const int hi_w = (u3 >> 3) & 3;
    const int j_w  = u3 & 7;

    ((uint32_t*)hbuf)[tid] = 0u;   // zero-init both buffers (512 dwords)

    half4_t xA = *(const half4_t*)(xgp);
    half4_t xB = *(const half4_t*)(xgp + 4096);
    float hprev = 0.0f;
    __syncthreads();

#define SCAN_STEP(RB, X, TT)                                                   \
    {                                                                          \
        half8_t hB0 = *(const half8_t*)&hbuf[RB][0][hi][c4][0];                \
        half8_t hB1 = *(const half8_t*)&hbuf[RB][1][hi][c4][0];                \
        half8_t hB2 = *(const half8_t*)&hbuf[RB][2][hi][c4][0];                \
        half8_t hB3 = *(const half8_t*)&hbuf[RB][3][hi][c4][0];                \
        f32x4_t r = {0.f,0.f,0.f,0.f}, z = {0.f,0.f,0.f,0.f}, n = {0.f,0.f,0.f,0.f}; \
        r = MFMA32(Ar[0], hB0, r); z = MFMA32(Az[0], hB0, z); n = MFMA32(Ahn[0], hB0, n); \
        r = MFMA32(Ar[1], hB1, r); z = MFMA32(Az[1], hB1, z); n = MFMA32(Ahn[1], hB1, n); \
        r = MFMA32(Ar[2], hB2, r); z = MFMA32(Az[2], hB2, z); n = MFMA32(Ahn[2], hB2, n); \
        r = MFMA32(Ar[3], hB3, r); z = MFMA32(Az[3], hB3, z); n = MFMA32(Ahn[3], hB3, n); \
        float srr = pick_reg(r, srcaddr, sel) + (float)(X)[0];                 \
        float szz = pick_reg(z, srcaddr, sel) + (float)(X)[1];                 \
        float shn = pick_reg(n, srcaddr, sel) + bhn;                           \
        float sxn = (float)(X)[2];                                             \
        float rg   = fast_sigmoid(srr);                                        \
        float zg   = fast_sigmoid(szz);                                        \
        float ng   = fast_tanh(sxn + rg * shn);                                \
        float hnew = ng + zg * (hprev - ng);                                   \
        hprev = hnew;                                                          \
        _Float16 h16 = (_Float16)hnew;                                         \
        hbuf[(RB) ^ 1][kc_w][hi_w][c4][j_w] = h16;                             \
        hsb[(size_t)(TT) * HID_] = h16;                                        \
        asm volatile("s_waitcnt lgkmcnt(0)" ::: "memory");                     \
        __builtin_amdgcn_s_barrier();                                          \
    }

    for (int t = 0; t < T_; t += 2) {
        const size_t o2 = (size_t)((t + 2 < T_) ? t + 2 : T_ - 1) * 4096;
        const size_t o3 = (size_t)((t + 3 < T_) ? t + 3 : T_ - 1) * 4096;
        half4_t xC = *(const half4_t*)(xgp + o2);
        SCAN_STEP(0, xA, t);
        half4_t xD = *(const half4_t*)(xgp + o3);
        SCAN_STEP(1, xB, t + 1);
        xA = xC; xB = xD;
    }
#undef SCAN_STEP
}

// ---------------------------------------------------------------------------
// Kernel 3: out = hs @ W_post.T + b_post as MFMA GEMM, no LDS, no barriers.
// Block (b, ch, i): out tile [30 t-rows x 256 v] = A(30x128, fp16 hs rows
// t = t0+3m) @ B(128x256, W_post16). 8 waves: wave wv owns v in
// [32wv, 32wv+32): 2 M-tiles x 2 N-tiles x 4 K-chunks = 16 MFMA.
// A/B packed with the k-slot convention k = 32kc+8hi+j on both operands
// (proven in k_scan); D: col=lane&15, row=4hi+q (proven round 4).
// Rows 30/31: loads clamped to m=29, stores masked. jc=0/31 + i=0/31 zeros.
// ---------------------------------------------------------------------------
__global__ __launch_bounds__(512, 2) void k_post(const _Float16* __restrict__ w16,
                                                 const float* __restrict__ b_post,
                                                 const _Float16* __restrict__ hs,
                                                 float* __restrict__ out) {
    const int tid  = threadIdx.x;
    const int blk  = blockIdx.x;       // 64*3*32
    const int i    = blk & 31;
    const int rest = blk >> 5;
    const int ch   = rest % 3;
    const int b    = rest / 3;
    float* outb = out + ((size_t)(b * 3 + ch) * 1024 + i * 32) * VMAX_;

    const float4 z4 = {0.f, 0.f, 0.f, 0.f};
    if (i == 0 || i == 31) {           // full 32x256 zero tile
        float4* o4 = (float4*)outb;    // 2048 float4
#pragma unroll
        for (int k = 0; k < 4; ++k) o4[k * 512 + tid] = z4;
        return;
    }
    // zero rows jc=0 and jc=31 (64 float4 each)
    if (tid < 64)       ((float4*)outb)[tid] = z4;
    else if (tid < 128) ((float4*)(outb + 31 * VMAX_))[tid - 64] = z4;

    const int wv   = tid >> 6;
    const int lane = tid & 63;
    const int lo   = lane & 15;
    const int hi   = lane >> 4;
    const int t0   = (i - 1) * 90 + ch;    // t = t0 + 3*m, m = jc-1 in [0,30)
    const _Float16* hsb = hs + (size_t)b * T_ * HID_;

    half8_t Af[2][4], Bf[2][4];
#pragma unroll
    for (int mt = 0; mt < 2; ++mt) {
        int m = mt * 16 + lo; if (m > 29) m = 29;          // clamp pad rows
        const _Float16* ap = hsb + (size_t)(t0 + 3 * m) * HID_ + hi * 8;
#pragma unroll
        for (int kc = 0; kc < 4; ++kc) Af[mt][kc] = *(const half8_t*)(ap + kc * 32);
    }
    const int vb = wv * 32;
#pragma unroll
    for (int nt = 0; nt < 2; ++nt) {
        const _Float16* bp = w16 + (size_t)(vb + nt * 16 + lo) * HID_ + hi * 8;
#pragma unroll
        for (int kc = 0; kc < 4; ++kc) Bf[nt][kc] = *(const half8_t*)(bp + kc * 32);
    }
    const float bp0 = b_post[vb + lo];
    const float bp1 = b_post[vb + 16 + lo];

    f32x4_t a00 = {0.f,0.f,0.f,0.f}, a01 = a00, a10 = a00, a11 = a00;
#pragma unroll
    for (int kc = 0; kc < 4; ++kc) {
        a00 = MFMA32(Af[0][kc], Bf[0][kc], a00);
        a01 = MFMA32(Af[0][kc], Bf[1][kc], a01);
        a10 = MFMA32(Af[1][kc], Bf[0][kc], a10);
        a11 = MFMA32(Af[1][kc], Bf[1][kc], a11);
    }

#pragma unroll
    for (int q = 0; q < 4; ++q) {
        {   // mt = 0: m = 4*hi+q in [0,16) always valid
            float* orow = outb + (size_t)(1 + 4 * hi + q) * VMAX_;
            orow[vb + lo]      = a00[q] + bp0;
            orow[vb + 16 + lo] = a01[q] + bp1;
        }
        if (4 * hi + q <= 13) {   // mt = 1: m = 16+4*hi+q must be <= 29
            float* orow = outb + (size_t)(17 + 4 * hi + q) * VMAX_;
            orow[vb + lo]      = a10[q] + bp0;
            orow[vb + 16 + lo] = a11[q] + bp1;
        }
    }
}

extern "C" void kernel_launch(void* const* d_in, const int* in_sizes, int n_in,
                              void* d_out, int out_size, void* d_ws, size_t ws_size,
                              hipStream_t stream) {
    const float* x      = (const float*)d_in[0];
    const float* W_pre  = (const float*)d_in[1];
    const float* b_pre  = (const float*)d_in[2];
    const float* W_ih   = (const float*)d_in[3];
    const float* b_ih   = (const float*)d_in[4];
    const float* W_hh   = (const float*)d_in[5];
    const float* b_hh   = (const float*)d_in[6];
    const float* W_post = (const float*)d_in[7];
    const float* b_post = (const float*)d_in[8];
    float* out = (float*)d_out;

    // ws layout: pre16 (11.06 MB, reused as w16 after k_xg) | xg (176.9 MB) |
    //            hs16 (44.2 MB). Total 232.3 MB (proven to fit: rounds 3/4
    //            ran the identical FULL layout).
    const size_t pre_bytes = (size_t)NG_ * T_ * 256;
    const size_t xg_bytes  = (size_t)NG_ * T_ * 512 * 8;
    _Float16* pre16 = (_Float16*)d_ws;
    _Float16* w16   = (_Float16*)d_ws;                    // overwrites pre16 after k_xg
    _Float16* xg    = (_Float16*)((char*)d_ws + pre_bytes);
    _Float16* hs16  = (_Float16*)((char*)d_ws + pre_bytes + xg_bytes);

    k_pre <<<21600, 256, 0, stream>>>(x, W_pre, b_pre, pre16);
    k_xg  <<<NG_ * TCH_, 512, 0, stream>>>(W_ih, b_ih, b_hh, pre16, xg);
    k_wcvt<<<128, 256, 0, stream>>>(W_post, w16);
    k_scan<<<NG_, 512, 0, stream>>>(W_hh, b_hh, xg, hs16);
    k_post<<<6144, 512, 0, stream>>>(w16, b_post, hs16, out);
}

// Round 6
// 1985.512 us; speedup vs baseline: 1.2308x; 1.0665x over previous
//
#include <hip/hip_runtime.h>
#include <cstdint>

#define B_    64
#define T_    2700
#define HID_  128
#define PRE_  32
#define VMAX_ 256
#define NG_   16   // batch groups = k_scan grid
#define NB_   4    // batches per group
#define TCH_  27   // k_xg t-chunks
#define TSZ_  100  // t per chunk

typedef _Float16 half2_t __attribute__((ext_vector_type(2)));
typedef _Float16 half4_t __attribute__((ext_vector_type(4)));
typedef _Float16 half8_t __attribute__((ext_vector_type(8)));
typedef float    f32x4_t __attribute__((ext_vector_type(4)));
union H8u { half8_t v; half2_t p[4]; };

#define MFMA32(A, Bv, C) __builtin_amdgcn_mfma_f32_16x16x32_f16((A), (Bv), (C), 0, 0, 0)

#if __has_builtin(__builtin_amdgcn_fdot2)
__device__ __forceinline__ float FDOT2(half2_t a, half2_t b, float c) {
    return __builtin_amdgcn_fdot2(a, b, c, false);
}
#else
__device__ __forceinline__ float FDOT2(half2_t a, half2_t b, float c) {
    return c + (float)a[0] * (float)b[0] + (float)a[1] * (float)b[1];
}
#endif

__device__ __forceinline__ half2_t mk2(float a, float b) {
    half2_t r; r[0] = (_Float16)a; r[1] = (_Float16)b; return r;
}
__device__ __forceinline__ float fast_sigmoid(float x) {
    float t = __builtin_amdgcn_exp2f(-1.4426950408889634f * x);
    return __builtin_amdgcn_rcpf(1.0f + t);
}
__device__ __forceinline__ float fast_tanh(float x) {
    float t = __builtin_amdgcn_exp2f(2.885390081777927f * x);
    return 1.0f - 2.0f * __builtin_amdgcn_rcpf(t + 1.0f);
}
// pull the (sel)-th accumulator element from source lane (addr>>2)
__device__ __forceinline__ float pick_reg(f32x4_t v, int addr, int sel) {
    float t0 = __int_as_float(__builtin_amdgcn_ds_bpermute(addr, __float_as_int(v[0])));
    float t1 = __int_as_float(__builtin_amdgcn_ds_bpermute(addr, __float_as_int(v[1])));
    float t2 = __int_as_float(__builtin_amdgcn_ds_bpermute(addr, __float_as_int(v[2])));
    float t3 = __int_as_float(__builtin_amdgcn_ds_bpermute(addr, __float_as_int(v[3])));
    float a = (sel & 1) ? t1 : t0;
    float b = (sel & 1) ? t3 : t2;
    return (sel & 2) ? b : a;
}

// ---------------------------------------------------------------------------
// Kernel 1: neighborhood assembly + pre = sigmoid(inp @ W_pre.T + b_pre).
// fp16 output packed for K=32 B-fragments: pre16[g][t][hi(4)][cs(4)][j(8)].
// ---------------------------------------------------------------------------
__global__ __launch_bounds__(256) void k_pre(const float* __restrict__ x,
                                             const float* __restrict__ W_pre,
                                             const float* __restrict__ b_pre,
                                             _Float16* __restrict__ pre16) {
    int tid  = blockIdx.x * 256 + threadIdx.x;   // < 64*900*3*32
    int i    = tid & 31;          // k index into PRE
    int rest = tid >> 5;          // (b*900+p)*3 + c
    int c    = rest % 3;
    int r2   = rest / 3;          // b*900 + p
    int p    = r2 % 900;
    int b    = r2 / 900;
    int r    = p / 30;
    int cc   = p - r * 30;
    const float* xb = x + b * 3072 + r * 32 + cc;  // x[b][ch][r][cc] at xb[ch*1024]
    float f0 = xb[0],    f1  = xb[1024], f2  = xb[2048];   // tl
    float f3 = xb[1],    f4  = xb[1025], f5  = xb[2049];   // tc
    float f6 = xb[2],    f7  = xb[1026], f8  = xb[2050];   // tr
    float f9 = xb[32],   f10 = xb[1056], f11 = xb[2080];   // lf
    float ct0 = xb[33],  ct1 = xb[1057];                   // ct[0..1]
    float f12 = (c >= 1) ? ct0 : -1.0f;
    float f13 = (c >= 2) ? ct1 : -1.0f;
    const float* w = W_pre + i * 14;
    float d = b_pre[i];
    d += f0*w[0]  + f1*w[1]  + f2*w[2]  + f3*w[3]  + f4*w[4]  + f5*w[5]  + f6*w[6]
       + f7*w[7]  + f8*w[8]  + f9*w[9]  + f10*w[10] + f11*w[11] + f12*w[12] + f13*w[13];

    int t  = p * 3 + c;           // time index
    int g  = b >> 2;              // batch group
    int cs = b & 3;               // batch slot within group
    size_t base = ((size_t)g * T_ + t) * 128;     // 128 halves per (g,t)
    int idx = ((i >> 3) << 5) | (cs << 3) | (i & 7);   // [hi][cs][j]
    pre16[base + idx] = (_Float16)fast_sigmoid(d);
}

// ---------------------------------------------------------------------------
// Kernel 1b: xg[g][t][tid] = {xr', xz', xn', 0} fp16 (8B/thread), where
// u3 = (tid>>6)*16 + ((tid&63)>>2), c4 = tid&3 — matches k_scan's lane
// ownership exactly, so k_scan loads its values with one coalesced 8B load.
// xr' = pre.Wr + b_ih_r + b_hh_r; xz' likewise; xn' = pre.Wn + b_ih_n.
// ---------------------------------------------------------------------------
__global__ __launch_bounds__(512) void k_xg(const float* __restrict__ W_ih,
                                            const float* __restrict__ b_ih,
                                            const float* __restrict__ b_hh,
                                            const _Float16* __restrict__ pre16,
                                            _Float16* __restrict__ xg16) {
    const int tid = threadIdx.x;
    const int g   = blockIdx.x / TCH_;
    const int tc  = blockIdx.x % TCH_;
    const int u3  = (tid >> 6) * 16 + ((tid & 63) >> 2);
    const int c4  = tid & 3;

    half2_t wr[16], wz[16], wn[16];
    const float* Wr = W_ih + (size_t)u3 * PRE_;
    const float* Wz = W_ih + (size_t)(128 + u3) * PRE_;
    const float* Wn = W_ih + (size_t)(256 + u3) * PRE_;
#pragma unroll
    for (int k2 = 0; k2 < 16; ++k2) {
        wr[k2] = mk2(Wr[2*k2], Wr[2*k2 + 1]);
        wz[k2] = mk2(Wz[2*k2], Wz[2*k2 + 1]);
        wn[k2] = mk2(Wn[2*k2], Wn[2*k2 + 1]);
    }
    const float br = b_ih[u3] + b_hh[u3];
    const float bz = b_ih[128 + u3] + b_hh[128 + u3];
    const float bn = b_ih[256 + u3];

    const char* preg = (const char*)pre16 + ((size_t)g * T_ + (size_t)tc * TSZ_) * 256 + c4 * 16;
    H8u pc0, pc1, pc2, pc3;
    pc0.v = *(const half8_t*)(preg +   0);
    pc1.v = *(const half8_t*)(preg +  64);
    pc2.v = *(const half8_t*)(preg + 128);
    pc3.v = *(const half8_t*)(preg + 192);

    for (int tt = 0; tt < TSZ_; ++tt) {
        const int ttn = (tt + 1 < TSZ_) ? tt + 1 : tt;
        H8u n0, n1, n2, n3;
        n0.v = *(const half8_t*)(preg + (size_t)ttn * 256 +   0);
        n1.v = *(const half8_t*)(preg + (size_t)ttn * 256 +  64);
        n2.v = *(const half8_t*)(preg + (size_t)ttn * 256 + 128);
        n3.v = *(const half8_t*)(preg + (size_t)ttn * 256 + 192);

        float ar = br, az = bz, an = bn;
#pragma unroll
        for (int j2 = 0; j2 < 4; ++j2) { ar = FDOT2(wr[ 0+j2], pc0.p[j2], ar); az = FDOT2(wz[ 0+j2], pc0.p[j2], az); an = FDOT2(wn[ 0+j2], pc0.p[j2], an); }
#pragma unroll
        for (int j2 = 0; j2 < 4; ++j2) { ar = FDOT2(wr[ 4+j2], pc1.p[j2], ar); az = FDOT2(wz[ 4+j2], pc1.p[j2], az); an = FDOT2(wn[ 4+j2], pc1.p[j2], an); }
#pragma unroll
        for (int j2 = 0; j2 < 4; ++j2) { ar = FDOT2(wr[ 8+j2], pc2.p[j2], ar); az = FDOT2(wz[ 8+j2], pc2.p[j2], az); an = FDOT2(wn[ 8+j2], pc2.p[j2], an); }
#pragma unroll
        for (int j2 = 0; j2 < 4; ++j2) { ar = FDOT2(wr[12+j2], pc3.p[j2], ar); az = FDOT2(wz[12+j2], pc3.p[j2], az); an = FDOT2(wn[12+j2], pc3.p[j2], an); }

        const size_t t = (size_t)tc * TSZ_ + tt;
        half4_t o;
        o[0] = (_Float16)ar; o[1] = (_Float16)az; o[2] = (_Float16)an; o[3] = (_Float16)0.f;
        *(half4_t*)((char*)xg16 + (((size_t)g * T_ + t) * 512 + tid) * 8) = o;
        pc0 = n0; pc1 = n1; pc2 = n2; pc3 = n3;
    }
}

// ---------------------------------------------------------------------------
// Kernel 1c: W_post -> fp16, row-major [256][128]. Written into the dead
// pre16 region (runs after k_xg).
// ---------------------------------------------------------------------------
__global__ __launch_bounds__(256) void k_wcvt(const float* __restrict__ W_post,
                                              _Float16* __restrict__ w16) {
    int idx = blockIdx.x * 256 + threadIdx.x;   // 32768
    w16[idx] = (_Float16)W_post[idx];
}

// ---------------------------------------------------------------------------
// Kernel 2: persistent GRU scan — EXACT round-3 structure (measured 1408 us).
// Rolled t-loop, dynamic rb = t&1, 1-step xg prefetch. Rounds 4/5 proved the
// x2-unrolled/static-index/2-step-prefetch variant is ~330 us SLOWER (1735);
// do not re-unroll. 16 blocks x 512 thr, 4 batch chains each; wave w owns
// gate rows [16w,16w+16); 12 MFMA 16x16x32 per wave; bpermute epilogue
// (1 nonlinearity per lane); raw lgkmcnt(0)+s_barrier keeps vmem in flight.
// ---------------------------------------------------------------------------
__global__ __launch_bounds__(512, 1) void k_scan(const float* __restrict__ W_hh,
                                                 const float* __restrict__ b_hh,
                                                 const _Float16* __restrict__ xg16,
                                                 _Float16* __restrict__ hs16) {
    // h state in B-frag layout: [buf][kc][hi][c][j], u = kc*32 + hi*8 + j
    __shared__ __align__(16) _Float16 hbuf[2][4][4][4][8];   // 2 KB

    const int tid  = threadIdx.x;
    const int g    = blockIdx.x;
    const int w    = tid >> 6;
    const int lane = tid & 63;
    const int lo   = lane & 15;
    const int hi   = lane >> 4;
    const int c4   = lane & 3;
    const int row  = w * 16 + lo;

    half8_t Ar[4], Az[4], Ahn[4];
#pragma unroll
    for (int kc = 0; kc < 4; ++kc) {
        half8_t ar, az, an;
#pragma unroll
        for (int j = 0; j < 8; ++j) {
            int k = kc * 32 + hi * 8 + j;
            ar[j] = (_Float16)W_hh[row * HID_ + k];
            az[j] = (_Float16)W_hh[(128 + row) * HID_ + k];
            an[j] = (_Float16)W_hh[(256 + row) * HID_ + k];
        }
        Ar[kc] = ar; Az[kc] = az; Ahn[kc] = an;
    }

    const int u3 = w * 16 + (lane >> 2);
    const float bhn = b_hh[256 + u3];
    const int srcaddr = ((((lane >> 4) << 4) | c4) << 2);
    const int sel     = (lane >> 2) & 3;

    const char* xgp = (const char*)xg16 + ((size_t)g * T_ * 512 + tid) * 8;
    _Float16* hsb = hs16 + (size_t)(g * NB_ + c4) * T_ * HID_ + u3;

    const int kc_w = u3 >> 5;
    const int hi_w = (u3 >> 3) & 3;
    const int j_w  = u3 & 7;

    ((uint32_t*)hbuf)[tid] = 0u;   // zero-init both buffers (512 dwords)

    half4_t xh = *(const half4_t*)(xgp);
    float hprev = 0.0f;
    __syncthreads();

    for (int t = 0; t < T_; ++t) {
        const int tn = (t + 1 < T_) ? (t + 1) : t;
        half4_t xhn = *(const half4_t*)(xgp + (size_t)tn * 4096);

        const int rb = t & 1;
        half8_t hB[4];
#pragma unroll
        for (int kc = 0; kc < 4; ++kc)
            hB[kc] = *(const half8_t*)&hbuf[rb][kc][hi][c4][0];   // 4-way broadcast b128

        const f32x4_t Z4 = {0.f, 0.f, 0.f, 0.f};
        f32x4_t r = Z4, z = Z4, n = Z4;
        r = MFMA32(Ar[0],  hB[0], r);
        z = MFMA32(Az[0],  hB[0], z);
        n = MFMA32(Ahn[0], hB[0], n);
        r = MFMA32(Ar[1],  hB[1], r);
        z = MFMA32(Az[1],  hB[1], z);
        n = MFMA32(Ahn[1], hB[1], n);
        r = MFMA32(Ar[2],  hB[2], r);
        z = MFMA32(Az[2],  hB[2], z);
        n = MFMA32(Ahn[2], hB[2], n);
        r = MFMA32(Ar[3],  hB[3], r);
        z = MFMA32(Az[3],  hB[3], z);
        n = MFMA32(Ahn[3], hB[3], n);

        float srr = pick_reg(r, srcaddr, sel) + (float)xh[0];
        float szz = pick_reg(z, srcaddr, sel) + (float)xh[1];
        float shn = pick_reg(n, srcaddr, sel) + bhn;
        float sxn = (float)xh[2];

        float rg   = fast_sigmoid(srr);
        float zg   = fast_sigmoid(szz);
        float ng   = fast_tanh(sxn + rg * shn);
        float hnew = ng + zg * (hprev - ng);
        hprev = hnew;
        _Float16 h16 = (_Float16)hnew;

        hbuf[rb ^ 1][kc_w][hi_w][c4][j_w] = h16;
        hsb[(size_t)t * HID_] = h16;

        xh = xhn;

        // LDS-only barrier: hbuf write visible; vmem stays in flight.
        asm volatile("s_waitcnt lgkmcnt(0)" ::: "memory");
        __builtin_amdgcn_s_barrier();
    }
}

// ---------------------------------------------------------------------------
// Kernel 3: out = hs @ W_post.T + b_post as MFMA GEMM, no LDS, no barriers.
// (round-5 proven: non-scan time 693 -> 378 us, absmax unchanged)
// Block (b, ch, i): out tile [30 t-rows x 256 v] = A(30x128, fp16 hs rows
// t = t0+3m) @ B(128x256, W_post16). 8 waves: wave wv owns v in
// [32wv, 32wv+32): 2 M-tiles x 2 N-tiles x 4 K-chunks = 16 MFMA.
// A/B packed with the k-slot convention k = 32kc+8hi+j on both operands;
// D: col=lane&15, row=4hi+q. Rows 30/31: loads clamped, stores masked.
// ---------------------------------------------------------------------------
__global__ __launch_bounds__(512, 2) void k_post(const _Float16* __restrict__ w16,
                                                 const float* __restrict__ b_post,
                                                 const _Float16* __restrict__ hs,
                                                 float* __restrict__ out) {
    const int tid  = threadIdx.x;
    const int blk  = blockIdx.x;       // 64*3*32
    const int i    = blk & 31;
    const int rest = blk >> 5;
    const int ch   = rest % 3;
    const int b    = rest / 3;
    float* outb = out + ((size_t)(b * 3 + ch) * 1024 + i * 32) * VMAX_;

    const float4 z4 = {0.f, 0.f, 0.f, 0.f};
    if (i == 0 || i == 31) {           // full 32x256 zero tile
        float4* o4 = (float4*)outb;    // 2048 float4
#pragma unroll
        for (int k = 0; k < 4; ++k) o4[k * 512 + tid] = z4;
        return;
    }
    // zero rows jc=0 and jc=31 (64 float4 each)
    if (tid < 64)       ((float4*)outb)[tid] = z4;
    else if (tid < 128) ((float4*)(outb + 31 * VMAX_))[tid - 64] = z4;

    const int wv   = tid >> 6;
    const int lane = tid & 63;
    const int lo   = lane & 15;
    const int hi   = lane >> 4;
    const int t0   = (i - 1) * 90 + ch;    // t = t0 + 3*m, m = jc-1 in [0,30)
    const _Float16* hsb = hs + (size_t)b * T_ * HID_;

    half8_t Af[2][4], Bf[2][4];
#pragma unroll
    for (int mt = 0; mt < 2; ++mt) {
        int m = mt * 16 + lo; if (m > 29) m = 29;          // clamp pad rows
        const _Float16* ap = hsb + (size_t)(t0 + 3 * m) * HID_ + hi * 8;
#pragma unroll
        for (int kc = 0; kc < 4; ++kc) Af[mt][kc] = *(const half8_t*)(ap + kc * 32);
    }
    const int vb = wv * 32;
#pragma unroll
    for (int nt = 0; nt < 2; ++nt) {
        const _Float16* bp = w16 + (size_t)(vb + nt * 16 + lo) * HID_ + hi * 8;
#pragma unroll
        for (int kc = 0; kc < 4; ++kc) Bf[nt][kc] = *(const half8_t*)(bp + kc * 32);
    }
    const float bp0 = b_post[vb + lo];
    const float bp1 = b_post[vb + 16 + lo];

    f32x4_t a00 = {0.f,0.f,0.f,0.f}, a01 = a00, a10 = a00, a11 = a00;
#pragma unroll
    for (int kc = 0; kc < 4; ++kc) {
        a00 = MFMA32(Af[0][kc], Bf[0][kc], a00);
        a01 = MFMA32(Af[0][kc], Bf[1][kc], a01);
        a10 = MFMA32(Af[1][kc], Bf[0][kc], a10);
        a11 = MFMA32(Af[1][kc], Bf[1][kc], a11);
    }

#pragma unroll
    for (int q = 0; q < 4; ++q) {
        {   // mt = 0: m = 4*hi+q in [0,16) always valid
            float* orow = outb + (size_t)(1 + 4 * hi + q) * VMAX_;
            orow[vb + lo]      = a00[q] + bp0;
            orow[vb + 16 + lo] = a01[q] + bp1;
        }
        if (4 * hi + q <= 13) {   // mt = 1: m = 16+4*hi+q must be <= 29
            float* orow = outb + (size_t)(17 + 4 * hi + q) * VMAX_;
            orow[vb + lo]      = a10[q] + bp0;
            orow[vb + 16 + lo] = a11[q] + bp1;
        }
    }
}

extern "C" void kernel_launch(void* const* d_in, const int* in_sizes, int n_in,
                              void* d_out, int out_size, void* d_ws, size_t ws_size,
                              hipStream_t stream) {
    const float* x      = (const float*)d_in[0];
    const float* W_pre  = (const float*)d_in[1];
    const float* b_pre  = (const float*)d_in[2];
    const float* W_ih   = (const float*)d_in[3];
    const float* b_ih   = (const float*)d_in[4];
    const float* W_hh   = (const float*)d_in[5];
    const float* b_hh   = (const float*)d_in[6];
    const float* W_post = (const float*)d_in[7];
    const float* b_post = (const float*)d_in[8];
    float* out = (float*)d_out;

    // ws layout: pre16 (11.06 MB, reused as w16 after k_xg) | xg (176.9 MB) |
    //            hs16 (44.2 MB). Total 232.3 MB (rounds 3-5 ran this layout).
    const size_t pre_bytes = (size_t)NG_ * T_ * 256;
    const size_t xg_bytes  = (size_t)NG_ * T_ * 512 * 8;
    _Float16* pre16 = (_Float16*)d_ws;
    _Float16* w16   = (_Float16*)d_ws;                    // overwrites pre16 after k_xg
    _Float16* xg    = (_Float16*)((char*)d_ws + pre_bytes);
    _Float16* hs16  = (_Float16*)((char*)d_ws + pre_bytes + xg_bytes);

    k_pre <<<21600, 256, 0, stream>>>(x, W_pre, b_pre, pre16);
    k_xg  <<<NG_ * TCH_, 512, 0, stream>>>(W_ih, b_ih, b_hh, pre16, xg);
    k_wcvt<<<128, 256, 0, stream>>>(W_post, w16);
    k_scan<<<NG_, 512, 0, stream>>>(W_hh, b_hh, xg, hs16);
    k_post<<<6144, 512, 0, stream>>>(w16, b_post, hs16, out);
}